// Round 2
// baseline (753.187 us; speedup 1.0000x reference)
//
#include <hip/hip_runtime.h>

#define TSEQ 512

typedef _Float16 half8 __attribute__((ext_vector_type(8)));
typedef __attribute__((ext_vector_type(4))) float f32x4;

#define MFMAH(a,b,c) __builtin_amdgcn_mfma_f32_16x16x32_f16(a,b,c,0,0,0)

static __device__ __forceinline__ float sigm(float x){ return __builtin_amdgcn_rcpf(1.0f + __expf(-x)); }
static __device__ __forceinline__ float tanh_f(float x){ return 1.0f - 2.0f*__builtin_amdgcn_rcpf(__expf(2.0f*x)+1.0f); }

static __device__ __forceinline__ short f2h(float v){
  union { _Float16 h; short s; } u; u.h = (_Float16)v; return u.s;
}

// wait lgkmcnt(0) only (vmcnt left alone so x-prefetch stays in flight)
static __device__ __forceinline__ void lds_drain(){
  __builtin_amdgcn_s_waitcnt(0xC07F);
  __asm__ __volatile__("" ::: "memory");
}

// raw workgroup barrier WITHOUT the implicit vmcnt(0) drain of __syncthreads.
// callers must lds_drain() first so LDS writes are visible to other waves.
static __device__ __forceinline__ void bar(){
  __asm__ __volatile__("" ::: "memory");
  __builtin_amdgcn_s_barrier();
  __asm__ __volatile__("" ::: "memory");
}

// 512 WGs x 512 thr (8 waves). __launch_bounds__(512,2) -> VGPR=80 (NO
// spills; R1's (512,4) forced VGPR=64 and spilled the 64-VGPR weight set
// to scratch: WRITE_SIZE 8KB->30MB, the whole regression).
// 80 VGPR <= 128 already permits 4 waves/SIMD in HW, so TWO 8-wave WGs
// co-reside per CU -- occupancy comes from grid=512, not launch bounds.
// WG owns batch rows [2b, 2b+2). Co-resident WGs are INDEPENDENT
// recurrence chains: their barrier/LDS-latency stalls interleave, filling
// the ~65% idle pipe slots the single-WG lockstep version exposed.
// Rows 2-3 of the 16-row MFMA tile compute garbage (clamped x reads,
// never stored) -- instruction count identical to the 4-row version.
// Wave wv: gemm gm=wv>>2 (0: layer0 -> gates0(i+1); 1: layer1 -> gates1(i)),
// j-quarter p=wv&3, tiles q=0..3 (gate index) at cols q*64+16p+lr.
// fp16 weights as B-frags in 64 VGPRs; bias folded into MFMA C operand.
// Activations fp16 in LDS, frag-ordered, double-buffered, ONE raw
// s_barrier/step (lgkm-only drain: x-prefetch vmcnt stays in flight).
// Gate redistribution: in-wave LDS roundtrip (masked b128 writes [q][j][m],
// conflict-free b32 reads), no bpermute, no extra barrier.
// act arrs: 0,1 x buf0/1; 2,3 h0 buf0/1; 4,5 h1 buf0/1.
// A-frag offset for lane (lq,lr), chunk F: F*128 + lq*32 + lr*8 (shorts).
extern "C" __global__ void __launch_bounds__(512, 2)
lstm_h16c(const float* __restrict__ x,
          const float* __restrict__ wih0, const float* __restrict__ whh0,
          const float* __restrict__ bih0, const float* __restrict__ bhh0,
          const float* __restrict__ wih1, const float* __restrict__ whh1,
          const float* __restrict__ bih1, const float* __restrict__ bhh1,
          const float* __restrict__ fcw,  const float* __restrict__ fcb,
          float* __restrict__ out)
{
  __shared__ __align__(16) short act[6][256];
  __shared__ __align__(16) float gbuf[2][1024];   // [gemm][q*256 + j*4 + m]
  __shared__ float fcpart[16];

  const int tid = threadIdx.x;
  const int wv  = tid >> 6;
  const int gm  = wv >> 2;
  const int p   = wv & 3;
  const int ln  = tid & 63;
  const int lq  = ln >> 4;
  const int lr  = ln & 15;
  const int b0  = blockIdx.x << 1;               // 2 batch rows per WG
  const int jc  = (p << 4) + lr;                 // j (0..63): gemm col / cell col
  // h/x staging slot for cell thread (k=jc, m=lq):
  const int si  = (((jc>>5)*4 + ((jc>>3)&3))*4 + lq)*8 + (jc&7);
  // A-frag read offset for chunk F=0 (F adds +128): shorts
  const int foff = lq*32 + lr*8;
  float* const gme = &gbuf[gm][0];
  const bool wlane = (lq == 0);

  // ---- one-time: fp16 weight B-frags [op][F][q] = 64 VGPR ----
  half8 W[2][2][4];
  {
    const float* w_op[2] = { gm ? wih1 : wih0, gm ? whh1 : whh0 };
#pragma unroll
    for (int op = 0; op < 2; ++op)
#pragma unroll
      for (int F = 0; F < 2; ++F)
#pragma unroll
        for (int q = 0; q < 4; ++q){
          const float* src = w_op[op] + ((q<<6) + jc)*64 + F*32 + lq*8;
#pragma unroll
          for (int e = 0; e < 8; ++e)
            W[op][F][q][e] = (_Float16)src[e];
        }
  }
  // bias in C operand: Bq[q] = broadcast(bias_q(jc))
  f32x4 Bq[4];
  {
    const float* bi = gm ? bih1 : bih0;
    const float* bh = gm ? bhh1 : bhh0;
#pragma unroll
    for (int q = 0; q < 4; ++q){
      float b = bi[(q<<6)+jc] + bh[(q<<6)+jc];
      Bq[q][0] = b; Bq[q][1] = b; Bq[q][2] = b; Bq[q][3] = b;
    }
  }

  // rows 2-3 of the tile are garbage; clamp their x reads in-bounds
  const int xrow = (lq < 2) ? (b0 + lq) : b0;
  const float* xq = x + (size_t)xrow*(TSEQ*64) + jc;

  float cst = 0.f, hval = 0.f, xv = 0.f;
  half8 aF[4];   // persistent frag regs (masked loads leave lr>=4 lanes stale: harmless rows 4-15)
#pragma unroll
  for (int f = 0; f < 4; ++f) aF[f] = (half8){0,0,0,0,0,0,0,0};

  // ---- prologue ----
  for (int idx = tid; idx < 2*256; idx += 512) act[4 + (idx>>8)][idx & 255] = 0;
  if (gm == 0){
    act[0][si] = f2h(xq[0]);     // x(0) -> buf0
    act[1][si] = f2h(xq[64]);    // x(1) -> buf1
    xv = xq[128];                // x(2)
  }
  __syncthreads();

  if (gm == 0){   // gates0(0) = x(0)·Wih0 + bias (h0(-1)=0) -> cell0 -> h0(0) buf0
    if (lr < 4){
      aF[0] = *(const half8*)(&act[0][0] + foff);
      aF[1] = *(const half8*)(&act[0][0] + foff + 128);
    }
    f32x4 acc[4];
#pragma unroll
    for (int q = 0; q < 4; ++q){
      acc[q] = MFMAH(aF[0], W[0][0][q], Bq[q]);
      acc[q] = MFMAH(aF[1], W[0][1][q], acc[q]);
    }
    if (wlane){
#pragma unroll
      for (int q = 0; q < 4; ++q) *(f32x4*)&gme[q*256 + jc*4] = acc[q];
    }
    lds_drain();
    float gi = sigm  (gme[0*256 + jc*4 + lq]);
    float gf = sigm  (gme[1*256 + jc*4 + lq]);
    float gg = tanh_f(gme[2*256 + jc*4 + lq]);
    float go = sigm  (gme[3*256 + jc*4 + lq]);
    cst  = gf*cst + gi*gg;
    hval = go * tanh_f(cst);
    act[2][si] = f2h(hval);
  }
  __syncthreads();

  // ---- main loops: divergent by gemm, ONE raw barrier per iteration each ----
  if (gm == 1){
#pragma unroll 2
    for (int i = 0; i < TSEQ; ++i){
      const int cb = i & 1, nb = cb ^ 1;
      // gates1(i) = h0(i)·Wih1 + h1(i-1)·Whh1 + bias
      if (lr < 4){
        aF[0] = *(const half8*)(&act[2+cb][0] + foff);
        aF[1] = *(const half8*)(&act[2+cb][0] + foff + 128);
        aF[2] = *(const half8*)(&act[4+nb][0] + foff);
        aF[3] = *(const half8*)(&act[4+nb][0] + foff + 128);
      }
      f32x4 acc[4];
#pragma unroll
      for (int q = 0; q < 4; ++q){
        acc[q] = MFMAH(aF[0], W[0][0][q], Bq[q]);
        acc[q] = MFMAH(aF[1], W[0][1][q], acc[q]);
        acc[q] = MFMAH(aF[2], W[1][0][q], acc[q]);
        acc[q] = MFMAH(aF[3], W[1][1][q], acc[q]);
      }
      if (wlane){
#pragma unroll
        for (int q = 0; q < 4; ++q) *(f32x4*)&gme[q*256 + jc*4] = acc[q];
      }
      lds_drain();
      float gi = sigm  (gme[0*256 + jc*4 + lq]);
      float gf = sigm  (gme[1*256 + jc*4 + lq]);
      float gg = tanh_f(gme[2*256 + jc*4 + lq]);
      float go = sigm  (gme[3*256 + jc*4 + lq]);
      cst  = gf*cst + gi*gg;
      hval = go * tanh_f(cst);
      act[4+cb][si] = f2h(hval);     // h1(i)
      lds_drain();
      bar();
    }
  } else {
#pragma unroll 2
    for (int i = 0; i < TSEQ; ++i){
      const int cb = i & 1, nb = cb ^ 1;
      if (i < TSEQ-1){
        // gates0(i+1) = x(i+1)·Wih0 + h0(i)·Whh0 + bias
        if (lr < 4){
          aF[0] = *(const half8*)(&act[0+nb][0] + foff);
          aF[1] = *(const half8*)(&act[0+nb][0] + foff + 128);
          aF[2] = *(const half8*)(&act[2+cb][0] + foff);
          aF[3] = *(const half8*)(&act[2+cb][0] + foff + 128);
        }
        f32x4 acc[4];
#pragma unroll
        for (int q = 0; q < 4; ++q){
          acc[q] = MFMAH(aF[0], W[0][0][q], Bq[q]);
          acc[q] = MFMAH(aF[1], W[0][1][q], acc[q]);
          acc[q] = MFMAH(aF[2], W[1][0][q], acc[q]);
          acc[q] = MFMAH(aF[3], W[1][1][q], acc[q]);
        }
        if (wlane){
#pragma unroll
          for (int q = 0; q < 4; ++q) *(f32x4*)&gme[q*256 + jc*4] = acc[q];
        }
        lds_drain();
        float gi = sigm  (gme[0*256 + jc*4 + lq]);
        float gf = sigm  (gme[1*256 + jc*4 + lq]);
        float gg = tanh_f(gme[2*256 + jc*4 + lq]);
        float go = sigm  (gme[3*256 + jc*4 + lq]);
        cst  = gf*cst + gi*gg;
        hval = go * tanh_f(cst);
        act[2+nb][si] = f2h(hval);   // h0(i+1)
        if (i < TSEQ-2) act[0+cb][si] = f2h(xv);   // stage x(i+2)
        int tn = i + 3; if (tn > TSEQ-1) tn = TSEQ-1;
        xv = xq[tn << 6];            // prefetch x(i+3)
      }
      lds_drain();
      bar();
    }
  }

  // ---- FC head: gemm1 waves hold h1(T-1) for (m=lq, j=jc) ----
  if (gm == 1){
    float v = hval * fcw[jc];
    v += __shfl_xor(v, 1); v += __shfl_xor(v, 2);
    v += __shfl_xor(v, 4); v += __shfl_xor(v, 8);
    if (lr == 0) fcpart[p*4 + lq] = v;
  }
  __syncthreads();
  if (tid < 2)
    out[b0 + tid] = fcpart[tid] + fcpart[4+tid] + fcpart[8+tid] + fcpart[12+tid] + fcb[0];
}

extern "C" void kernel_launch(void* const* d_in, const int* in_sizes, int n_in,
                              void* d_out, int out_size, void* d_ws, size_t ws_size,
                              hipStream_t stream) {
  const float* x    = (const float*)d_in[0];
  const float* wih0 = (const float*)d_in[1];
  const float* whh0 = (const float*)d_in[2];
  const float* bih0 = (const float*)d_in[3];
  const float* bhh0 = (const float*)d_in[4];
  const float* wih1 = (const float*)d_in[5];
  const float* whh1 = (const float*)d_in[6];
  const float* bih1 = (const float*)d_in[7];
  const float* bhh1 = (const float*)d_in[8];
  const float* fcw  = (const float*)d_in[9];
  const float* fcb  = (const float*)d_in[10];
  float* out = (float*)d_out;

  hipLaunchKernelGGL(lstm_h16c, dim3(512), dim3(512), 0, stream,
                     x, wih0, whh0, bih0, bhh0, wih1, whh1, bih1, bhh1, fcw, fcb, out);
}

// Round 3
// 666.629 us; speedup vs baseline: 1.1298x; 1.1298x over previous
//
#include <hip/hip_runtime.h>

#define TSEQ 512

typedef _Float16 half8 __attribute__((ext_vector_type(8)));
typedef __attribute__((ext_vector_type(4))) float f32x4;

#define MFMAH(a,b,c) __builtin_amdgcn_mfma_f32_16x16x32_f16(a,b,c,0,0,0)

static __device__ __forceinline__ float sigm(float x){ return __builtin_amdgcn_rcpf(1.0f + __expf(-x)); }
static __device__ __forceinline__ float tanh_f(float x){ return 1.0f - 2.0f*__builtin_amdgcn_rcpf(__expf(2.0f*x)+1.0f); }

static __device__ __forceinline__ short f2h(float v){
  union { _Float16 h; short s; } u; u.h = (_Float16)v; return u.s;
}

// wait lgkmcnt(0) only (vmcnt left alone so x-prefetch stays in flight)
static __device__ __forceinline__ void lds_drain(){
  __builtin_amdgcn_s_waitcnt(0xC07F);
  __asm__ __volatile__("" ::: "memory");
}

// raw workgroup barrier WITHOUT the implicit vmcnt(0) drain of __syncthreads.
// callers must lds_drain() first so LDS writes are visible to other waves.
static __device__ __forceinline__ void bar(){
  __asm__ __volatile__("" ::: "memory");
  __builtin_amdgcn_s_barrier();
  __asm__ __volatile__("" ::: "memory");
}

// 512 WGs x 512 thr (8 waves), 2 batch rows/WG. GOAL: 2 co-resident WGs/CU
// (4 waves/SIMD) = independent recurrence chains whose latency stalls
// interleave. Cliff discovered R0-R2: co-residency needs TOTAL regs
// (VGPR+AGPR unified on gfx950) <= 128/wave. R0/R2 (~144 live) -> 1 WG/CU;
// R1's forced 128 budget spilled (30MB scratch). This version DIETS ~28 regs:
//  - bias as 4 scalars applied post-roundtrip (was 16-reg f32x4 Bq in MFMA C)
//  - F-outer MFMA split: 2 live A-frags, not 4
//  - unmasked frag loads (garbage A rows 4-15 only pollute their own unused
//    D rows), no persistent aF array
// then forces <=128 via __launch_bounds__(512,4). Check: WRITE_SIZE must
// stay ~KB (spill tripwire), OccupancyPercent ~41+.
// Wave wv: gemm gm=wv>>2 (0: layer0 -> gates0(i+1); 1: layer1 -> gates1(i)),
// j-quarter p=wv&3, tiles q=0..3 (gate index) at cols q*64+16p+lr.
// fp16 weights as B-frags in 64 VGPRs. Activations fp16 in LDS,
// frag-ordered, double-buffered, ONE raw s_barrier/step (lgkm-only drain:
// x-prefetch vmcnt stays in flight). Gate redistribution: in-wave LDS
// roundtrip (masked b128 writes [q][j][m], conflict-free b32 reads).
// act arrs: 0,1 x buf0/1; 2,3 h0 buf0/1; 4,5 h1 buf0/1.
// A-frag offset for lane (lq,lr), chunk F: F*128 + lq*32 + lr*8 (shorts).
extern "C" __global__ void __launch_bounds__(512, 4)
lstm_h16c(const float* __restrict__ x,
          const float* __restrict__ wih0, const float* __restrict__ whh0,
          const float* __restrict__ bih0, const float* __restrict__ bhh0,
          const float* __restrict__ wih1, const float* __restrict__ whh1,
          const float* __restrict__ bih1, const float* __restrict__ bhh1,
          const float* __restrict__ fcw,  const float* __restrict__ fcb,
          float* __restrict__ out)
{
  __shared__ __align__(16) short act[6][256];
  __shared__ __align__(16) float gbuf[2][1024];   // [gemm][q*256 + j*4 + m]
  __shared__ float fcpart[16];

  const int tid = threadIdx.x;
  const int wv  = tid >> 6;
  const int gm  = wv >> 2;
  const int p   = wv & 3;
  const int ln  = tid & 63;
  const int lq  = ln >> 4;
  const int lr  = ln & 15;
  const int b0  = blockIdx.x << 1;               // 2 batch rows per WG
  const int jc  = (p << 4) + lr;                 // j (0..63): gemm col / cell col
  // h/x staging slot for cell thread (k=jc, m=lq):
  const int si  = (((jc>>5)*4 + ((jc>>3)&3))*4 + lq)*8 + (jc&7);
  // A-frag read offset for chunk F=0 (F adds +128): shorts
  const int foff = lq*32 + lr*8;
  float* const gme = &gbuf[gm][0];
  const bool wlane = (lq == 0);

  // ---- one-time: fp16 weight B-frags [op][F][q] = 64 VGPR ----
  half8 W[2][2][4];
  {
    const float* w_op[2] = { gm ? wih1 : wih0, gm ? whh1 : whh0 };
#pragma unroll
    for (int op = 0; op < 2; ++op)
#pragma unroll
      for (int F = 0; F < 2; ++F)
#pragma unroll
        for (int q = 0; q < 4; ++q){
          const float* src = w_op[op] + ((q<<6) + jc)*64 + F*32 + lq*8;
#pragma unroll
          for (int e = 0; e < 8; ++e)
            W[op][F][q][e] = (_Float16)src[e];
        }
  }
  // bias as 4 scalars for this cell thread's column jc (applied post-MFMA)
  float bq0, bq1, bq2, bq3;
  {
    const float* bi = gm ? bih1 : bih0;
    const float* bh = gm ? bhh1 : bhh0;
    bq0 = bi[0*64+jc] + bh[0*64+jc];
    bq1 = bi[1*64+jc] + bh[1*64+jc];
    bq2 = bi[2*64+jc] + bh[2*64+jc];
    bq3 = bi[3*64+jc] + bh[3*64+jc];
  }
  const f32x4 Zq = {0.f, 0.f, 0.f, 0.f};

  // rows 2-3 of the tile are garbage; clamp their x reads in-bounds
  const int xrow = (lq < 2) ? (b0 + lq) : b0;
  const float* xq = x + (size_t)xrow*(TSEQ*64) + jc;

  float cst = 0.f, hval = 0.f, xv = 0.f;

  // ---- prologue ----
  for (int idx = tid; idx < 2*256; idx += 512) act[4 + (idx>>8)][idx & 255] = 0;
  if (gm == 0){
    act[0][si] = f2h(xq[0]);     // x(0) -> buf0
    act[1][si] = f2h(xq[64]);    // x(1) -> buf1
    xv = xq[128];                // x(2)
  }
  __syncthreads();

  if (gm == 0){   // gates0(0) = x(0)·Wih0 + bias (h0(-1)=0) -> cell0 -> h0(0) buf0
    f32x4 acc[4];
    {
      half8 a0 = *(const half8*)(&act[0][0] + foff);
#pragma unroll
      for (int q = 0; q < 4; ++q) acc[q] = MFMAH(a0, W[0][0][q], Zq);
      a0 = *(const half8*)(&act[0][0] + foff + 128);
#pragma unroll
      for (int q = 0; q < 4; ++q) acc[q] = MFMAH(a0, W[0][1][q], acc[q]);
    }
    if (wlane){
#pragma unroll
      for (int q = 0; q < 4; ++q) *(f32x4*)&gme[q*256 + jc*4] = acc[q];
    }
    lds_drain();
    float gi = sigm  (gme[0*256 + jc*4 + lq] + bq0);
    float gf = sigm  (gme[1*256 + jc*4 + lq] + bq1);
    float gg = tanh_f(gme[2*256 + jc*4 + lq] + bq2);
    float go = sigm  (gme[3*256 + jc*4 + lq] + bq3);
    cst  = gf*cst + gi*gg;
    hval = go * tanh_f(cst);
    act[2][si] = f2h(hval);
  }
  __syncthreads();

  // ---- main loops: divergent by gemm, ONE raw barrier per iteration each ----
  if (gm == 1){
#pragma unroll 2
    for (int i = 0; i < TSEQ; ++i){
      const int cb = i & 1, nb = cb ^ 1;
      // gates1(i) = h0(i)·Wih1 + h1(i-1)·Whh1 + bias
      f32x4 acc[4];
      {
        half8 a0 = *(const half8*)(&act[2+cb][0] + foff);
        half8 a1 = *(const half8*)(&act[4+nb][0] + foff);
#pragma unroll
        for (int q = 0; q < 4; ++q){
          acc[q] = MFMAH(a0, W[0][0][q], Zq);
          acc[q] = MFMAH(a1, W[1][0][q], acc[q]);
        }
        a0 = *(const half8*)(&act[2+cb][0] + foff + 128);
        a1 = *(const half8*)(&act[4+nb][0] + foff + 128);
#pragma unroll
        for (int q = 0; q < 4; ++q){
          acc[q] = MFMAH(a0, W[0][1][q], acc[q]);
          acc[q] = MFMAH(a1, W[1][1][q], acc[q]);
        }
      }
      if (wlane){
#pragma unroll
        for (int q = 0; q < 4; ++q) *(f32x4*)&gme[q*256 + jc*4] = acc[q];
      }
      lds_drain();
      float gi = sigm  (gme[0*256 + jc*4 + lq] + bq0);
      float gf = sigm  (gme[1*256 + jc*4 + lq] + bq1);
      float gg = tanh_f(gme[2*256 + jc*4 + lq] + bq2);
      float go = sigm  (gme[3*256 + jc*4 + lq] + bq3);
      cst  = gf*cst + gi*gg;
      hval = go * tanh_f(cst);
      act[4+cb][si] = f2h(hval);     // h1(i)
      lds_drain();
      bar();
    }
  } else {
#pragma unroll 2
    for (int i = 0; i < TSEQ; ++i){
      const int cb = i & 1, nb = cb ^ 1;
      if (i < TSEQ-1){
        // gates0(i+1) = x(i+1)·Wih0 + h0(i)·Whh0 + bias
        f32x4 acc[4];
        {
          half8 a0 = *(const half8*)(&act[0+nb][0] + foff);
          half8 a1 = *(const half8*)(&act[2+cb][0] + foff);
#pragma unroll
          for (int q = 0; q < 4; ++q){
            acc[q] = MFMAH(a0, W[0][0][q], Zq);
            acc[q] = MFMAH(a1, W[1][0][q], acc[q]);
          }
          a0 = *(const half8*)(&act[0+nb][0] + foff + 128);
          a1 = *(const half8*)(&act[2+cb][0] + foff + 128);
#pragma unroll
          for (int q = 0; q < 4; ++q){
            acc[q] = MFMAH(a0, W[0][1][q], acc[q]);
            acc[q] = MFMAH(a1, W[1][1][q], acc[q]);
          }
        }
        if (wlane){
#pragma unroll
          for (int q = 0; q < 4; ++q) *(f32x4*)&gme[q*256 + jc*4] = acc[q];
        }
        lds_drain();
        float gi = sigm  (gme[0*256 + jc*4 + lq] + bq0);
        float gf = sigm  (gme[1*256 + jc*4 + lq] + bq1);
        float gg = tanh_f(gme[2*256 + jc*4 + lq] + bq2);
        float go = sigm  (gme[3*256 + jc*4 + lq] + bq3);
        cst  = gf*cst + gi*gg;
        hval = go * tanh_f(cst);
        act[2+nb][si] = f2h(hval);   // h0(i+1)
        if (i < TSEQ-2) act[0+cb][si] = f2h(xv);   // stage x(i+2)
        int tn = i + 3; if (tn > TSEQ-1) tn = TSEQ-1;
        xv = xq[tn << 6];            // prefetch x(i+3)
      }
      lds_drain();
      bar();
    }
  }

  // ---- FC head: gemm1 waves hold h1(T-1) for (m=lq, j=jc) ----
  if (gm == 1){
    float v = hval * fcw[jc];
    v += __shfl_xor(v, 1); v += __shfl_xor(v, 2);
    v += __shfl_xor(v, 4); v += __shfl_xor(v, 8);
    if (lr == 0) fcpart[p*4 + lq] = v;
  }
  __syncthreads();
  if (tid < 2)
    out[b0 + tid] = fcpart[tid] + fcpart[4+tid] + fcpart[8+tid] + fcpart[12+tid] + fcb[0];
}

extern "C" void kernel_launch(void* const* d_in, const int* in_sizes, int n_in,
                              void* d_out, int out_size, void* d_ws, size_t ws_size,
                              hipStream_t stream) {
  const float* x    = (const float*)d_in[0];
  const float* wih0 = (const float*)d_in[1];
  const float* whh0 = (const float*)d_in[2];
  const float* bih0 = (const float*)d_in[3];
  const float* bhh0 = (const float*)d_in[4];
  const float* wih1 = (const float*)d_in[5];
  const float* whh1 = (const float*)d_in[6];
  const float* bih1 = (const float*)d_in[7];
  const float* bhh1 = (const float*)d_in[8];
  const float* fcw  = (const float*)d_in[9];
  const float* fcb  = (const float*)d_in[10];
  float* out = (float*)d_out;

  hipLaunchKernelGGL(lstm_h16c, dim3(512), dim3(512), 0, stream,
                     x, wih0, whh0, bih0, bhh0, wih1, whh1, bih1, bhh1, fcw, fcb, out);
}

// Round 5
// 531.473 us; speedup vs baseline: 1.4172x; 1.2543x over previous
//
#include <hip/hip_runtime.h>

#define TSEQ 512

typedef _Float16 half8 __attribute__((ext_vector_type(8)));
typedef __attribute__((ext_vector_type(4))) float f32x4;
typedef short short4v __attribute__((ext_vector_type(4)));

#define MFMAH(a,b,c) __builtin_amdgcn_mfma_f32_16x16x32_f16(a,b,c,0,0,0)

static __device__ __forceinline__ float sigm(float x){ return __builtin_amdgcn_rcpf(1.0f + __expf(-x)); }
static __device__ __forceinline__ float tanh_f(float x){ return 1.0f - 2.0f*__builtin_amdgcn_rcpf(__expf(2.0f*x)+1.0f); }

static __device__ __forceinline__ short f2h(float v){
  union { _Float16 h; short s; } u; u.h = (_Float16)v; return u.s;
}

// wait lgkmcnt(0) only (vmcnt left alone so x-prefetch stays in flight)
static __device__ __forceinline__ void lds_drain(){
  __builtin_amdgcn_s_waitcnt(0xC07F);
  __asm__ __volatile__("" ::: "memory");
}

// raw workgroup barrier WITHOUT the implicit vmcnt(0) drain of __syncthreads.
// callers must lds_drain() first so LDS writes are visible to other waves.
static __device__ __forceinline__ void bar(){
  __asm__ __volatile__("" ::: "memory");
  __builtin_amdgcn_s_barrier();
  __asm__ __volatile__("" ::: "memory");
}

// SWAPPED-OPERAND LSTM: compute G^T = W · act^T instead of act · W^T.
//   A slot = WEIGHT tile (16 gate-rows x 32 k), static in 64 VGPRs.
//   B slot = ACTIVATION tile (32 k x 16 batch-cols) from LDS.
// R4 bug (absmax 0.079): operands were passed MFMAH(act, W, C) -- act in
// the A slot -- which computes D[batch][gate] (the OLD orientation) while
// the cell code read D[gate][batch]. Fixed: MFMAH(W, act, C).
//   D rows = gate dims, D cols = batch rows -> by C/D layout
//   (col=lane&15, row=(lane>>4)*4+reg) each lane holds ALL 4 gates of
//   4 hidden units for ONE batch row in its 16 acc regs: the cell
//   nonlinearity runs directly on acc. NO gate LDS roundtrip (R0-R3
//   spent ~240cyc/step + 16.7M bank-conflict cycles there).
// 16 D-columns = 16 batch rows at the same MFMA cost -> 4 rows/WG,
// grid=256 (1 WG/CU), __launch_bounds__(512,2): ~120 live regs, NO
// spill risk (R1/R3 lesson: 2-WG co-residency via (512,4) spills).
// Lane mappings (verified via R0's working si/foff algebra):
//   A: row=lane&15, k=(lane>>4)*8+e ; B: col=lane&15, k=(lane>>4)*8+e.
// act buffers [n][k], 72-short (144B) row stride: B-frag b128 reads are
// 2-way-conflict only (n and n+8 share banks; 2-way is free).
// Cols n>=4 are garbage-but-finite and column-isolated (x rows 4-15
// zeroed once, never written -> garbage cols evolve the x=0 trajectory,
// bounded by sigmoid/tanh saturation).
// Wave wv: gm=wv>>2 (0: layer0 -> gates0(i+1); 1: layer1 -> gates1(i)),
// p=wv&3: gate-row slice p*16..p*16+15 inside each 64-row gate block q.
// act arrs: 0,1 x buf0/1; 2,3 h0 buf0/1; 4,5 h1 buf0/1. ONE raw
// s_barrier/step, lgkm-only drain (x-prefetch vmcnt stays in flight).
#define SROW 72            // shorts per act row (144B stride)

extern "C" __global__ void __launch_bounds__(512, 2)
lstm_swp(const float* __restrict__ x,
         const float* __restrict__ wih0, const float* __restrict__ whh0,
         const float* __restrict__ bih0, const float* __restrict__ bhh0,
         const float* __restrict__ wih1, const float* __restrict__ whh1,
         const float* __restrict__ bih1, const float* __restrict__ bhh1,
         const float* __restrict__ fcw,  const float* __restrict__ fcb,
         float* __restrict__ out)
{
  __shared__ __align__(16) short act[6][16*SROW];
  __shared__ float fcpart[16];

  const int tid = threadIdx.x;
  const int wv  = tid >> 6;
  const int gm  = wv >> 2;
  const int p   = wv & 3;
  const int ln  = tid & 63;
  const int lq  = ln >> 4;                        // hi: k-chunk / unit-quad / x-row
  const int lr  = ln & 15;                        // batch col n / weight row
  const int b0  = blockIdx.x << 2;                // 4 batch rows per WG
  const int wrow = (p << 4) + lr;                 // weight row within gate block
  const int boff = lr*SROW + (lq << 3);           // B-frag short-offset (col=lr, k=lq*8)
  const int hwoff = lr*SROW + (p << 4) + (lq << 2); // h-write: row lr, units p*16+lq*4..+3
  const int soff  = lq*SROW + (p << 4) + lr;      // x-stage: row lq, k p*16+lr

  // ---- one-time: fp16 weight A-frags [op][F][q] = 64 VGPR ----
  half8 W[2][2][4];
  {
    const float* w_op[2] = { gm ? wih1 : wih0, gm ? whh1 : whh0 };
#pragma unroll
    for (int op = 0; op < 2; ++op)
#pragma unroll
      for (int F = 0; F < 2; ++F)
#pragma unroll
        for (int q = 0; q < 4; ++q){
          const float* src = w_op[op] + ((q<<6) + wrow)*64 + F*32 + lq*8;
#pragma unroll
          for (int e = 0; e < 8; ++e)
            W[op][F][q][e] = (_Float16)src[e];
        }
  }
  // bias as MFMA C-init: Bq[q][m] = bias(gate q, unit p*16+lq*4+m)
  f32x4 Bq[4];
  {
    const float* bi = gm ? bih1 : bih0;
    const float* bh = gm ? bhh1 : bhh0;
    const int ub = (p<<4) + (lq<<2);
#pragma unroll
    for (int q = 0; q < 4; ++q)
#pragma unroll
      for (int m = 0; m < 4; ++m)
        Bq[q][m] = bi[(q<<6)+ub+m] + bh[(q<<6)+ub+m];
  }

  // x pointer for stage thread (row lq in 0..3, all real), col p*16+lr
  const float* xq = x + (size_t)(b0 + lq)*(TSEQ*64) + (p<<4) + lr;

  float c0=0.f, c1=0.f, c2=0.f, c3=0.f;          // cell state, 4 units
  float hf0=0.f, hf1=0.f, hf2=0.f, hf3=0.f;      // h (float), 4 units
  float xv = 0.f;

  // ---- prologue: zero ALL act (x rows 4-15 must start 0, h1=0) ----
  {
    int* a32 = (int*)&act[0][0];
    for (int idx = tid; idx < 6*16*SROW/2; idx += 512) a32[idx] = 0;
  }
  __syncthreads();
  if (gm == 0){
    act[0][soff] = f2h(xq[0]);     // x(0) -> buf0
    act[1][soff] = f2h(xq[64]);    // x(1) -> buf1
    xv = xq[128];                  // x(2)
  }
  __syncthreads();

  if (gm == 0){   // gates0(0) = Wih0·x(0)^T + bias  (h0(-1)=0) -> h0(0) buf0
    const short* xb = &act[0][0];
    half8 bx0 = *(const half8*)(xb + boff);
    half8 bx1 = *(const half8*)(xb + boff + 32);
    f32x4 acc[4];
#pragma unroll
    for (int q = 0; q < 4; ++q){
      acc[q] = MFMAH(W[0][0][q], bx0, Bq[q]);
      acc[q] = MFMAH(W[0][1][q], bx1, acc[q]);
    }
    float gi, gf, gg, go;
    gi=sigm(acc[0][0]); gf=sigm(acc[1][0]); gg=tanh_f(acc[2][0]); go=sigm(acc[3][0]);
    c0 = gf*c0 + gi*gg; hf0 = go*tanh_f(c0);
    gi=sigm(acc[0][1]); gf=sigm(acc[1][1]); gg=tanh_f(acc[2][1]); go=sigm(acc[3][1]);
    c1 = gf*c1 + gi*gg; hf1 = go*tanh_f(c1);
    gi=sigm(acc[0][2]); gf=sigm(acc[1][2]); gg=tanh_f(acc[2][2]); go=sigm(acc[3][2]);
    c2 = gf*c2 + gi*gg; hf2 = go*tanh_f(c2);
    gi=sigm(acc[0][3]); gf=sigm(acc[1][3]); gg=tanh_f(acc[2][3]); go=sigm(acc[3][3]);
    c3 = gf*c3 + gi*gg; hf3 = go*tanh_f(c3);
    short4v hv = { f2h(hf0), f2h(hf1), f2h(hf2), f2h(hf3) };
    *(short4v*)(&act[2][0] + hwoff) = hv;
  }
  __syncthreads();

  // ---- main loops: divergent by gemm, ONE raw barrier per iteration ----
  if (gm == 1){
#pragma unroll 2
    for (int i = 0; i < TSEQ; ++i){
      const int cb = i & 1, nb = cb ^ 1;
      // gates1(i) = Wih1·h0(i)^T + Whh1·h1(i-1)^T + bias
      const short* h0b = &act[2+cb][0];
      const short* h1b = &act[4+nb][0];
      half8 ba0 = *(const half8*)(h0b + boff);
      half8 bb0 = *(const half8*)(h1b + boff);
      half8 ba1 = *(const half8*)(h0b + boff + 32);
      half8 bb1 = *(const half8*)(h1b + boff + 32);
      f32x4 acc[4];
#pragma unroll
      for (int q = 0; q < 4; ++q){
        acc[q] = MFMAH(W[0][0][q], ba0, Bq[q]);
        acc[q] = MFMAH(W[1][0][q], bb0, acc[q]);
        acc[q] = MFMAH(W[0][1][q], ba1, acc[q]);
        acc[q] = MFMAH(W[1][1][q], bb1, acc[q]);
      }
      float gi, gf, gg, go;
      gi=sigm(acc[0][0]); gf=sigm(acc[1][0]); gg=tanh_f(acc[2][0]); go=sigm(acc[3][0]);
      c0 = gf*c0 + gi*gg; hf0 = go*tanh_f(c0);
      gi=sigm(acc[0][1]); gf=sigm(acc[1][1]); gg=tanh_f(acc[2][1]); go=sigm(acc[3][1]);
      c1 = gf*c1 + gi*gg; hf1 = go*tanh_f(c1);
      gi=sigm(acc[0][2]); gf=sigm(acc[1][2]); gg=tanh_f(acc[2][2]); go=sigm(acc[3][2]);
      c2 = gf*c2 + gi*gg; hf2 = go*tanh_f(c2);
      gi=sigm(acc[0][3]); gf=sigm(acc[1][3]); gg=tanh_f(acc[2][3]); go=sigm(acc[3][3]);
      c3 = gf*c3 + gi*gg; hf3 = go*tanh_f(c3);
      short4v hv = { f2h(hf0), f2h(hf1), f2h(hf2), f2h(hf3) };
      *(short4v*)(&act[4+cb][0] + hwoff) = hv;   // h1(i)
      lds_drain();
      bar();
    }
  } else {
#pragma unroll 2
    for (int i = 0; i < TSEQ; ++i){
      const int cb = i & 1, nb = cb ^ 1;
      if (i < TSEQ-1){
        // gates0(i+1) = Wih0·x(i+1)^T + Whh0·h0(i)^T + bias
        const short* xb  = &act[0+nb][0];
        const short* h0b = &act[2+cb][0];
        half8 ba0 = *(const half8*)(xb  + boff);
        half8 bb0 = *(const half8*)(h0b + boff);
        half8 ba1 = *(const half8*)(xb  + boff + 32);
        half8 bb1 = *(const half8*)(h0b + boff + 32);
        f32x4 acc[4];
#pragma unroll
        for (int q = 0; q < 4; ++q){
          acc[q] = MFMAH(W[0][0][q], ba0, Bq[q]);
          acc[q] = MFMAH(W[1][0][q], bb0, acc[q]);
          acc[q] = MFMAH(W[0][1][q], ba1, acc[q]);
          acc[q] = MFMAH(W[1][1][q], bb1, acc[q]);
        }
        float gi, gf, gg, go;
        gi=sigm(acc[0][0]); gf=sigm(acc[1][0]); gg=tanh_f(acc[2][0]); go=sigm(acc[3][0]);
        c0 = gf*c0 + gi*gg; hf0 = go*tanh_f(c0);
        gi=sigm(acc[0][1]); gf=sigm(acc[1][1]); gg=tanh_f(acc[2][1]); go=sigm(acc[3][1]);
        c1 = gf*c1 + gi*gg; hf1 = go*tanh_f(c1);
        gi=sigm(acc[0][2]); gf=sigm(acc[1][2]); gg=tanh_f(acc[2][2]); go=sigm(acc[3][2]);
        c2 = gf*c2 + gi*gg; hf2 = go*tanh_f(c2);
        gi=sigm(acc[0][3]); gf=sigm(acc[1][3]); gg=tanh_f(acc[2][3]); go=sigm(acc[3][3]);
        c3 = gf*c3 + gi*gg; hf3 = go*tanh_f(c3);
        short4v hv = { f2h(hf0), f2h(hf1), f2h(hf2), f2h(hf3) };
        *(short4v*)(&act[2+nb][0] + hwoff) = hv;   // h0(i+1)
        if (i < TSEQ-2) act[0+cb][soff] = f2h(xv); // stage x(i+2)
        int tn = i + 3; if (tn > TSEQ-1) tn = TSEQ-1;
        xv = xq[tn << 6];                          // prefetch x(i+3)
      }
      lds_drain();
      bar();
    }
  }

  // ---- FC head: gm1 lanes hold h1(T-1) for (row lr, units p*16+lq*4..+3) ----
  if (gm == 1){
    const f32x4 fw = *(const f32x4*)(fcw + (p<<4) + (lq<<2));
    float v = hf0*fw[0] + hf1*fw[1] + hf2*fw[2] + hf3*fw[3];
    v += __shfl_xor(v, 16);
    v += __shfl_xor(v, 32);
    if (lq == 0 && lr < 4) fcpart[p*4 + lr] = v;
  }
  __syncthreads();
  if (tid < 4)
    out[b0 + tid] = fcpart[tid] + fcpart[4+tid] + fcpart[8+tid] + fcpart[12+tid] + fcb[0];
}

extern "C" void kernel_launch(void* const* d_in, const int* in_sizes, int n_in,
                              void* d_out, int out_size, void* d_ws, size_t ws_size,
                              hipStream_t stream) {
  const float* x    = (const float*)d_in[0];
  const float* wih0 = (const float*)d_in[1];
  const float* whh0 = (const float*)d_in[2];
  const float* bih0 = (const float*)d_in[3];
  const float* bhh0 = (const float*)d_in[4];
  const float* wih1 = (const float*)d_in[5];
  const float* whh1 = (const float*)d_in[6];
  const float* bih1 = (const float*)d_in[7];
  const float* bhh1 = (const float*)d_in[8];
  const float* fcw  = (const float*)d_in[9];
  const float* fcb  = (const float*)d_in[10];
  float* out = (float*)d_out;

  hipLaunchKernelGGL(lstm_swp, dim3(256), dim3(512), 0, stream,
                     x, wih0, whh0, bih0, bhh0, wih1, whh1, bih1, bhh1, fcw, fcb, out);
}